// Round 19
// baseline (39.905 us; speedup 1.0000x reference)
//
#include <hip/hip_runtime.h>
#include <stdint.h>

typedef unsigned short ushort_t;
typedef short short8 __attribute__((ext_vector_type(8)));
typedef float f32x4 __attribute__((ext_vector_type(4)));

#define CIN   64
#define COUT  128
#define BATCH 16
#define LPIX  1024               // 32*32
#define NTOT  (BATCH*LPIX)       // 16384
#define C2N   576                // CIN*9 features; c2 = f*64 + i (f-major)
#define PIXN  (BATCH*34*34)      // 18496 padded pixels
#define NSTEP2 72                // 8 basis slices (f=1..8) x 9 taps
#define KS    4                  // K-split: 18 steps (2 slices) per block
#define PART_ELEMS (NTOT*COUT)   // 2,097,152
#define FEAT_BLOCKS (PIXN/64)    // 289: 64 px x 64 ch per block
#define WPREP_BLOCKS 128         // one Cout row per block

// workspace layout (bytes)
#define FEAT_BYTES (PIXN*C2N*2)            // 21,307,392
#define W_OFF      FEAT_BYTES
#define W_BYTES    (COUT*NSTEP2*64*2)      // 1,179,648
#define BIAS_OFF   (W_OFF + W_BYTES)
#define PART_OFF   (BIAS_OFF + 512)
#define PART_BYTES (PART_ELEMS*2)          // bf16 partials: 4,194,304
#define WS_NEED    ((size_t)PART_OFF + (size_t)KS*PART_BYTES)

#define VM0() asm volatile("s_waitcnt vmcnt(0)" ::: "memory")
#define BAR() __builtin_amdgcn_s_barrier()

__device__ __forceinline__ ushort_t to_bf16(float f) {
  union { float f; uint32_t u; } v; v.f = f;
  uint32_t r = (v.u + 0x7fffu + ((v.u >> 16) & 1u)) >> 16;
  return (ushort_t)r;
}
__device__ __forceinline__ float from_bf16(ushort_t u) {
  union { uint32_t u; float f; } v; v.u = ((uint32_t)u) << 16;
  return v.f;
}

// H_0..H_7 (physicists') of x, plus silu(x) at [8]
__device__ __forceinline__ void basis9(float x, float* o) {
  float hm = 1.f, h = 2.f * x;
  o[0] = hm; o[1] = h;
#pragma unroll
  for (int n = 1; n < 7; ++n) {
    float nx = 2.f * x * h - 2.f * (float)n * hm;
    hm = h; h = nx;
    o[n + 1] = nx;
  }
  o[8] = x / (1.f + __expf(-x));
}

__device__ __forceinline__ void load16(const void* g, void* l) {
  __builtin_amdgcn_global_load_lds(
      (const __attribute__((address_space(1))) uint32_t*)g,
      (__attribute__((address_space(3))) uint32_t*)l, 16, 0, 0);
}

// -------- fused prep: W'+bias first, then feat (coalesced x-reads) --------
// feat block: 64 padded px x 64 ch. Lanes = consecutive PIXELS for the
// x-read (coalesced; old lane=ch pattern was stride-4KB). Hermite state in
// registers; per-basis LDS transpose [64][66] (write conflict-free, read
// 2-way=free); 128B/wave feat writes unchanged. Bit-identical feat values.
__global__ void prep_kernel(const float* __restrict__ x, ushort_t* __restrict__ feat,
                            const float* __restrict__ wb, const float* __restrict__ wsp,
                            const float* __restrict__ cc, ushort_t* __restrict__ W,
                            float* __restrict__ bias) {
  const int t = threadIdx.x;
  if (blockIdx.x < WPREP_BLOCKS) {
    __shared__ ushort_t wl[NSTEP2 * 64];          // 9216 B
    const int m = blockIdx.x;                     // Cout row
    if (t < 64) {
      const int i = t;                            // cin
      const int base = (i * COUT + m) * 9;
      const int r = ((((i >> 3) & 7) ^ (m & 7)) << 3) | (i & 7);
      float h0 = 0.f;
#pragma unroll
      for (int kk = 0; kk < 9; ++kk) {
        const float ws_ = wsp[base + kk];
        const float wbv = wb[base + kk];
        const float* cp = cc + (size_t)(base + kk) * 8;
        h0 += ws_ * cp[0];
#pragma unroll
        for (int sf = 1; sf <= 8; ++sf) {
          const float val = (sf < 8) ? ws_ * cp[sf] : wbv;
          wl[((sf - 1) * 9 + kk) * 64 + r] = to_bf16(val);
        }
      }
#pragma unroll
      for (int off = 32; off > 0; off >>= 1) h0 += __shfl_down(h0, off, 64);
      if (t == 0) bias[m] = h0;
    }
    __syncthreads();
    uint32_t* dst = (uint32_t*)&W[(size_t)m * (NSTEP2 * 64)];
    const uint32_t* src = (const uint32_t*)wl;
#pragma unroll
    for (int jj = 0; jj < 9; ++jj) dst[jj * 256 + t] = src[jj * 256 + t];
  } else {
    __shared__ ushort_t fl[64][66];               // 8448 B, +2 pad per row
    const int pg0 = (blockIdx.x - WPREP_BLOCKS) * 64;
    const int px = t & 63;                        // lane = pixel (coalesced x)
    const int cg = t >> 6;                        // channel group (16 ch)
    const int lane = t & 63;
    const int pg = pg0 + px;
    const int xx = pg % 34;
    const int rest = pg / 34;
    const int yy = rest % 34;
    const int bb = rest / 34;
    const bool inb = (xx >= 1 && xx <= 32 && yy >= 1 && yy <= 32);
    const float* xbase = x + (((bb * CIN) * 32 + (yy - 1)) * 32 + (xx - 1));
    float vv[16], h[16], hm[16];
#pragma unroll
    for (int ccn = 0; ccn < 16; ++ccn) {
      const int ch = cg * 16 + ccn;
      vv[ccn] = inb ? xbase[ch * LPIX] : 0.f;     // lanes: consecutive addrs
      hm[ccn] = 1.f;
      h[ccn] = 2.f * vv[ccn];
    }
#pragma unroll
    for (int f = 1; f <= 8; ++f) {
      // stage H_f (or silu at f=8) for 16 channels into the transpose tile
#pragma unroll
      for (int ccn = 0; ccn < 16; ++ccn) {
        const float o = (f == 8) ? (vv[ccn] / (1.f + __expf(-vv[ccn]))) : h[ccn];
        fl[px][cg * 16 + ccn] = to_bf16(o);
        if (f < 8) {                              // advance recurrence
          const float nx = 2.f * vv[ccn] * h[ccn] - 2.f * (float)f * hm[ccn];
          hm[ccn] = h[ccn];
          h[ccn] = nx;
        }
      }
      __syncthreads();
      // write out: wave lanes = consecutive ch -> 128B/wave stores
#pragma unroll
      for (int r = 0; r < 16; ++r) {
        const int row = cg * 16 + r;
        feat[(size_t)(pg0 + row) * C2N + f * 64 + lane] = fl[row][lane];
      }
      __syncthreads();                            // fl reused next f
    }
  }
}

// -------- GEMM (R18-verified best): 64x256, double-step, 4-deep A ---------
__global__ __launch_bounds__(256, 2) void gemm_kernel(const ushort_t* __restrict__ feat,
                                                      const ushort_t* __restrict__ W,
                                                      ushort_t* __restrict__ part) {
  __shared__ f32x4 smem4[76288 / 16];  // 74.5 KB: Ab(32K) + Hb(42.5K); reused
  ushort_t (*Ab)[4096] = (ushort_t(*)[4096])smem4;             // 4-slot A ring
  ushort_t* Hb = (ushort_t*)smem4 + 16384;                     // 2720 L x 8
  const int t = threadIdx.x;
  const int lane = t & 63;
  const int wn = t >> 6;               // 4 N-split waves, each 64x64

  const int logical = (blockIdx.x & 7) * 64 + (blockIdx.x >> 3);
  const int nb = logical >> 3;               // 0..63 (256-pixel N-tile)
  const int rem = logical & 7;
  const int mt = rem >> 2;                   // 0..1 (64-row M-tile)
  const int ksplit = rem & 3;                // 0..3
  const int lo = ksplit * 18;                // slices 2*ksplit, 2*ksplit+1

  const int b  = nb >> 2;                    // image
  const int y0 = (nb & 3) * 8;               // padded rows y0..y0+9
  const int pixbase = (b * 34 + y0) * 34;

  const char* Wb = (const char*)W + mt * 64 * (NSTEP2 * 64 * 2);
  const char* Fb = (const char*)feat;

  f32x4 acc[4][4];
#pragma unroll
  for (int a = 0; a < 4; ++a)
#pragma unroll
    for (int c = 0; c < 4; ++c) acc[a][c] = (f32x4)0.f;

  auto stage_halo = [&](int c2s) {           // basis f = c2s+1
    const char* base = Fb + (size_t)pixbase * (C2N * 2) + (c2s + 1) * 128;
#pragma unroll
    for (int it = 0; it < 11; ++it) {
      const int q = it * 256 + t;            // 2720 chunks: 340 L x 8
      if (q < 2720) {
        const int L = q >> 3;
        const int sl = (q & 7) ^ (L & 7);
        load16(base + L * (C2N * 2) + (sl << 4), &Hb[q * 8]);
      }
    }
  };

  auto stageA = [&](int p, int s) {          // 2 DMA loads/thread, always
#pragma unroll
    for (int q = 0; q < 2; ++q) {
      const int idx16 = q * 256 + t;         // 512 chunks: 64 rows x 8
      const int m = idx16 >> 3, ccn = idx16 & 7;
      load16(Wb + m * (NSTEP2 * 64 * 2) + s * 128 + ccn * 16, &Ab[p][idx16 * 8]);
    }
  };

  auto compute = [&](int p, int j) {         // tap j (compile-time)
    const int dy = j / 3, dx = j - dy * 3;
#pragma unroll
    for (int ks = 0; ks < 2; ++ks) {
      short8 av[4], bv[4];
      const int kslot = ks * 4 + (lane >> 4);
#pragma unroll
      for (int mf = 0; mf < 4; ++mf) {
        const int row = mf * 16 + (lane & 15);
        av[mf] = *(const short8*)&Ab[p][row * 64 + ((kslot ^ (row & 7)) << 3)];
      }
#pragma unroll
      for (int nf = 0; nf < 4; ++nf) {
        const int nl = wn * 64 + nf * 16 + (lane & 15);   // 0..255 in tile
        const int L = ((nl >> 5) + dy) * 34 + (nl & 31) + dx;
        bv[nf] = *(const short8*)&Hb[L * 64 + ((kslot ^ (L & 7)) << 3)];
      }
      __builtin_amdgcn_s_setprio(1);
#pragma unroll
      for (int mf = 0; mf < 4; ++mf)
#pragma unroll
        for (int nf = 0; nf < 4; ++nf)
          acc[mf][nf] = __builtin_amdgcn_mfma_f32_16x16x32_bf16(av[mf], bv[nf],
                                                                acc[mf][nf], 0, 0, 0);
      __builtin_amdgcn_s_setprio(0);
    }
  };

  // prologue: halo(slice0), A0->s0, A1->s1
  stage_halo(2 * ksplit);
  stageA(0, lo + 0);
  stageA(1, lo + 1);

  // R14 double-step schedule, slot = step & 3 throughout.
  VM0(); BAR(); stageA(2, lo + 2);  stageA(3, lo + 3);  compute(0, 0); compute(1, 1);
  VM0(); BAR(); stageA(0, lo + 4);  stageA(1, lo + 5);  compute(2, 2); compute(3, 3);
  VM0(); BAR(); stageA(2, lo + 6);  stageA(3, lo + 7);  compute(0, 4); compute(1, 5);
  VM0(); BAR(); stageA(0, lo + 8);  stageA(1, lo + 9);  compute(2, 6); compute(3, 7);
  VM0(); BAR();                                         compute(0, 8);
  BAR(); stage_halo(2 * ksplit + 1); stageA(2, lo + 10);
  VM0(); BAR(); stageA(3, lo + 11); stageA(0, lo + 12); compute(1, 0); compute(2, 1);
  VM0(); BAR(); stageA(1, lo + 13); stageA(2, lo + 14); compute(3, 2); compute(0, 3);
  VM0(); BAR(); stageA(3, lo + 15); stageA(0, lo + 16); compute(1, 4); compute(2, 5);
  VM0(); BAR(); stageA(1, lo + 17);                     compute(3, 6); compute(0, 7);
  VM0(); BAR();                                         compute(1, 8);

  // ---- epilogue: per-wave LDS transpose -> coalesced 16B NT stores ----
  BAR();                                     // all waves done reading Ab/Hb
  float* scr = (float*)smem4 + wn * 4352;    // 64 rows x 68 words, wave-priv
#pragma unroll
  for (int mf = 0; mf < 4; ++mf)
#pragma unroll
    for (int nf = 0; nf < 4; ++nf)
#pragma unroll
      for (int rg = 0; rg < 4; ++rg)
        scr[(mf * 16 + (lane >> 4) * 4 + rg) * 68 + nf * 16 + (lane & 15)] =
            acc[mf][nf][rg];
  ushort_t* dst = part + (size_t)ksplit * PART_ELEMS;
#pragma unroll
  for (int it = 0; it < 8; ++it) {
    const int row = it * 8 + (lane >> 3);    // m within wave tile
    const int c0 = (lane & 7) * 8;           // n within wave tile
    const float* p = &scr[row * 68 + c0];
    short8 v;
#pragma unroll
    for (int e = 0; e < 8; ++e) v[e] = (short)to_bf16(p[e]);
    const int m = mt * 64 + row;
    const int n = nb * 256 + wn * 64 + c0;
    const int bb = n >> 10, ll = n & 1023;
    __builtin_nontemporal_store(v, (short8*)&dst[(bb * COUT + m) * LPIX + ll]);
  }
}

// -------- add: out = bias[m] + sum of 4 bf16 partials (non-temporal) ------
__global__ void add_kernel(float* __restrict__ out, const ushort_t* __restrict__ part,
                           const float* __restrict__ bias) {
  const int i = (blockIdx.x * 256 + threadIdx.x) * 8;
  const float bv = bias[(i >> 10) & 127];
  f32x4 a0 = (f32x4)bv;
  f32x4 a1 = (f32x4)bv;
#pragma unroll
  for (int j = 0; j < KS; ++j) {
    const short8 pv = __builtin_nontemporal_load(
        (const short8*)&part[(size_t)j * PART_ELEMS + i]);
#pragma unroll
    for (int e = 0; e < 4; ++e) {
      a0[e] += from_bf16((ushort_t)pv[e]);
      a1[e] += from_bf16((ushort_t)pv[e + 4]);
    }
  }
  __builtin_nontemporal_store(a0, (f32x4*)&out[i]);
  __builtin_nontemporal_store(a1, (f32x4*)&out[i + 4]);
}

// ---------------- fallback (only if ws too small): direct evaluation -----
__global__ void naive_kernel(const float* __restrict__ x, const float* __restrict__ wb,
                             const float* __restrict__ wsp, const float* __restrict__ cc,
                             float* __restrict__ out) {
  const int idx = blockIdx.x * 256 + threadIdx.x;
  if (idx >= BATCH * COUT * LPIX) return;
  const int l = idx & 1023, o = (idx >> 10) & 127, b = idx >> 17;
  const int h = l >> 5, w = l & 31;
  float acc = 0.f;
  for (int i = 0; i < CIN; ++i)
    for (int kk = 0; kk < 9; ++kk) {
      const int yy = h + kk / 3 - 1, xx = w + kk % 3 - 1;
      const float v = (yy >= 0 && yy < 32 && xx >= 0 && xx < 32)
                          ? x[((b * CIN + i) * 32 + yy) * 32 + xx] : 0.f;
      float ftr[9];
      basis9(v, ftr);
      const int base = (i * COUT + o) * 9 + kk;
      const float* cp = cc + base * 8;
      float dot = 0.f;
#pragma unroll
      for (int f = 0; f < 8; ++f) dot += cp[f] * ftr[f];
      acc += wsp[base] * dot + wb[base] * ftr[8];
    }
  out[idx] = acc;
}

extern "C" void kernel_launch(void* const* d_in, const int* in_sizes, int n_in,
                              void* d_out, int out_size, void* d_ws, size_t ws_size,
                              hipStream_t stream) {
  const float* x  = (const float*)d_in[0];
  const float* wb = (const float*)d_in[1];
  const float* wsp = (const float*)d_in[2];
  const float* cc = (const float*)d_in[3];
  float* out = (float*)d_out;

  if (ws_size < WS_NEED) {
    naive_kernel<<<(BATCH * COUT * LPIX + 255) / 256, 256, 0, stream>>>(x, wb, wsp, cc, out);
    return;
  }

  char* ws = (char*)d_ws;
  ushort_t* feat = (ushort_t*)ws;
  ushort_t* W    = (ushort_t*)(ws + W_OFF);
  float* bias    = (float*)(ws + BIAS_OFF);
  ushort_t* part = (ushort_t*)(ws + PART_OFF);

  prep_kernel<<<WPREP_BLOCKS + FEAT_BLOCKS, 256, 0, stream>>>(x, feat, wb, wsp, cc, W, bias);
  gemm_kernel<<<64 * 2 * KS, 256, 0, stream>>>(feat, W, part);
  add_kernel<<<PART_ELEMS / 2048, 256, 0, stream>>>(out, part, bias);
}

// Round 20
// 38.630 us; speedup vs baseline: 1.0330x; 1.0330x over previous
//
#include <hip/hip_runtime.h>
#include <stdint.h>

typedef unsigned short ushort_t;
typedef short short8 __attribute__((ext_vector_type(8)));
typedef float f32x4 __attribute__((ext_vector_type(4)));

#define CIN   64
#define COUT  128
#define BATCH 16
#define LPIX  1024               // 32*32
#define NTOT  (BATCH*LPIX)       // 16384
#define C2N   576                // CIN*9 features; c2 = f*64 + i (f-major)
#define PIXN  (BATCH*34*34)      // 18496 padded pixels
#define NSTEP2 72                // 8 basis slices (f=1..8) x 9 taps
#define KS    4                  // K-split: 18 steps (2 slices) per block
#define PART_ELEMS (NTOT*COUT)   // 2,097,152
#define FEAT_BLOCKS (PIXN/4)     // 4624
#define WPREP_BLOCKS 128         // one Cout row per block

// workspace layout (bytes)
#define FEAT_BYTES (PIXN*C2N*2)            // 21,307,392
#define W_OFF      FEAT_BYTES
#define W_BYTES    (COUT*NSTEP2*64*2)      // 1,179,648
#define BIAS_OFF   (W_OFF + W_BYTES)
#define PART_OFF   (BIAS_OFF + 512)
#define PART_BYTES (PART_ELEMS*2)          // bf16 partials: 4,194,304
#define WS_NEED    ((size_t)PART_OFF + (size_t)KS*PART_BYTES)

#define VM0() asm volatile("s_waitcnt vmcnt(0)" ::: "memory")
#define BAR() __builtin_amdgcn_s_barrier()

__device__ __forceinline__ ushort_t to_bf16(float f) {
  union { float f; uint32_t u; } v; v.f = f;
  uint32_t r = (v.u + 0x7fffu + ((v.u >> 16) & 1u)) >> 16;
  return (ushort_t)r;
}
__device__ __forceinline__ float from_bf16(ushort_t u) {
  union { uint32_t u; float f; } v; v.u = ((uint32_t)u) << 16;
  return v.f;
}

// H_0..H_7 (physicists') of x, plus silu(x) at [8]
__device__ __forceinline__ void basis9(float x, float* o) {
  float hm = 1.f, h = 2.f * x;
  o[0] = hm; o[1] = h;
#pragma unroll
  for (int n = 1; n < 7; ++n) {
    float nx = 2.f * x * h - 2.f * (float)n * hm;
    hm = h; h = nx;
    o[n + 1] = nx;
  }
  o[8] = x / (1.f + __expf(-x));
}

__device__ __forceinline__ void load16(const void* g, void* l) {
  __builtin_amdgcn_global_load_lds(
      (const __attribute__((address_space(1))) uint32_t*)g,
      (__attribute__((address_space(3))) uint32_t*)l, 16, 0, 0);
}

// -------- fused prep (R16-verified): W'+bias first, then feat f=1..8 ------
__global__ void prep_kernel(const float* __restrict__ x, ushort_t* __restrict__ feat,
                            const float* __restrict__ wb, const float* __restrict__ wsp,
                            const float* __restrict__ cc, ushort_t* __restrict__ W,
                            float* __restrict__ bias) {
  const int t = threadIdx.x;
  if (blockIdx.x < WPREP_BLOCKS) {
    __shared__ ushort_t wl[NSTEP2 * 64];          // 9216 B
    const int m = blockIdx.x;                     // Cout row
    if (t < 64) {
      const int i = t;                            // cin
      const int base = (i * COUT + m) * 9;
      const int r = ((((i >> 3) & 7) ^ (m & 7)) << 3) | (i & 7);
      float h0 = 0.f;
#pragma unroll
      for (int kk = 0; kk < 9; ++kk) {
        const float ws_ = wsp[base + kk];
        const float wbv = wb[base + kk];
        const float* cp = cc + (size_t)(base + kk) * 8;
        h0 += ws_ * cp[0];
#pragma unroll
        for (int sf = 1; sf <= 8; ++sf) {
          const float val = (sf < 8) ? ws_ * cp[sf] : wbv;
          wl[((sf - 1) * 9 + kk) * 64 + r] = to_bf16(val);
        }
      }
#pragma unroll
      for (int off = 32; off > 0; off >>= 1) h0 += __shfl_down(h0, off, 64);
      if (t == 0) bias[m] = h0;
    }
    __syncthreads();
    uint32_t* dst = (uint32_t*)&W[(size_t)m * (NSTEP2 * 64)];
    const uint32_t* src = (const uint32_t*)wl;
#pragma unroll
    for (int jj = 0; jj < 9; ++jj) dst[jj * 256 + t] = src[jj * 256 + t];
  } else {
    const int lane = t & 63;                      // = cin index i
    const int pg = (blockIdx.x - WPREP_BLOCKS) * 4 + (t >> 6);  // padded pixel
    const int xx = pg % 34;
    const int rest = pg / 34;
    const int yy = rest % 34;
    const int bb = rest / 34;
    float v = 0.f;
    if (xx >= 1 && xx <= 32 && yy >= 1 && yy <= 32)
      v = x[((bb * CIN + lane) * 32 + (yy - 1)) * 32 + (xx - 1)];
    float o[9];
    basis9(v, o);
    ushort_t* dst = feat + (size_t)pg * C2N + lane;
#pragma unroll
    for (int f = 1; f < 9; ++f) dst[f * 64] = to_bf16(o[f]);  // skip f=0 plane
  }
}

// -------- GEMM (R18-verified best): 64x256, double-step, 4-deep A ---------
__global__ __launch_bounds__(256, 2) void gemm_kernel(const ushort_t* __restrict__ feat,
                                                      const ushort_t* __restrict__ W,
                                                      ushort_t* __restrict__ part) {
  __shared__ f32x4 smem4[76288 / 16];  // 74.5 KB: Ab(32K) + Hb(42.5K); reused
  ushort_t (*Ab)[4096] = (ushort_t(*)[4096])smem4;             // 4-slot A ring
  ushort_t* Hb = (ushort_t*)smem4 + 16384;                     // 2720 L x 8
  const int t = threadIdx.x;
  const int lane = t & 63;
  const int wn = t >> 6;               // 4 N-split waves, each 64x64

  const int logical = (blockIdx.x & 7) * 64 + (blockIdx.x >> 3);
  const int nb = logical >> 3;               // 0..63 (256-pixel N-tile)
  const int rem = logical & 7;
  const int mt = rem >> 2;                   // 0..1 (64-row M-tile)
  const int ksplit = rem & 3;                // 0..3
  const int lo = ksplit * 18;                // slices 2*ksplit, 2*ksplit+1

  const int b  = nb >> 2;                    // image
  const int y0 = (nb & 3) * 8;               // padded rows y0..y0+9
  const int pixbase = (b * 34 + y0) * 34;

  const char* Wb = (const char*)W + mt * 64 * (NSTEP2 * 64 * 2);
  const char* Fb = (const char*)feat;

  f32x4 acc[4][4];
#pragma unroll
  for (int a = 0; a < 4; ++a)
#pragma unroll
    for (int c = 0; c < 4; ++c) acc[a][c] = (f32x4)0.f;

  auto stage_halo = [&](int c2s) {           // basis f = c2s+1
    const char* base = Fb + (size_t)pixbase * (C2N * 2) + (c2s + 1) * 128;
#pragma unroll
    for (int it = 0; it < 11; ++it) {
      const int q = it * 256 + t;            // 2720 chunks: 340 L x 8
      if (q < 2720) {
        const int L = q >> 3;
        const int sl = (q & 7) ^ (L & 7);
        load16(base + L * (C2N * 2) + (sl << 4), &Hb[q * 8]);
      }
    }
  };

  auto stageA = [&](int p, int s) {          // 2 DMA loads/thread, always
#pragma unroll
    for (int q = 0; q < 2; ++q) {
      const int idx16 = q * 256 + t;         // 512 chunks: 64 rows x 8
      const int m = idx16 >> 3, ccn = idx16 & 7;
      load16(Wb + m * (NSTEP2 * 64 * 2) + s * 128 + ccn * 16, &Ab[p][idx16 * 8]);
    }
  };

  auto compute = [&](int p, int j) {         // tap j (compile-time)
    const int dy = j / 3, dx = j - dy * 3;
#pragma unroll
    for (int ks = 0; ks < 2; ++ks) {
      short8 av[4], bv[4];
      const int kslot = ks * 4 + (lane >> 4);
#pragma unroll
      for (int mf = 0; mf < 4; ++mf) {
        const int row = mf * 16 + (lane & 15);
        av[mf] = *(const short8*)&Ab[p][row * 64 + ((kslot ^ (row & 7)) << 3)];
      }
#pragma unroll
      for (int nf = 0; nf < 4; ++nf) {
        const int nl = wn * 64 + nf * 16 + (lane & 15);   // 0..255 in tile
        const int L = ((nl >> 5) + dy) * 34 + (nl & 31) + dx;
        bv[nf] = *(const short8*)&Hb[L * 64 + ((kslot ^ (L & 7)) << 3)];
      }
      __builtin_amdgcn_s_setprio(1);
#pragma unroll
      for (int mf = 0; mf < 4; ++mf)
#pragma unroll
        for (int nf = 0; nf < 4; ++nf)
          acc[mf][nf] = __builtin_amdgcn_mfma_f32_16x16x32_bf16(av[mf], bv[nf],
                                                                acc[mf][nf], 0, 0, 0);
      __builtin_amdgcn_s_setprio(0);
    }
  };

  // prologue: halo(slice0), A0->s0, A1->s1
  stage_halo(2 * ksplit);
  stageA(0, lo + 0);
  stageA(1, lo + 1);

  // R14 double-step schedule, slot = step & 3 throughout.
  VM0(); BAR(); stageA(2, lo + 2);  stageA(3, lo + 3);  compute(0, 0); compute(1, 1);
  VM0(); BAR(); stageA(0, lo + 4);  stageA(1, lo + 5);  compute(2, 2); compute(3, 3);
  VM0(); BAR(); stageA(2, lo + 6);  stageA(3, lo + 7);  compute(0, 4); compute(1, 5);
  VM0(); BAR(); stageA(0, lo + 8);  stageA(1, lo + 9);  compute(2, 6); compute(3, 7);
  VM0(); BAR();                                         compute(0, 8);
  BAR(); stage_halo(2 * ksplit + 1); stageA(2, lo + 10);
  VM0(); BAR(); stageA(3, lo + 11); stageA(0, lo + 12); compute(1, 0); compute(2, 1);
  VM0(); BAR(); stageA(1, lo + 13); stageA(2, lo + 14); compute(3, 2); compute(0, 3);
  VM0(); BAR(); stageA(3, lo + 15); stageA(0, lo + 16); compute(1, 4); compute(2, 5);
  VM0(); BAR(); stageA(1, lo + 17);                     compute(3, 6); compute(0, 7);
  VM0(); BAR();                                         compute(1, 8);

  // ---- epilogue: per-wave LDS transpose -> coalesced 16B NT stores ----
  BAR();                                     // all waves done reading Ab/Hb
  float* scr = (float*)smem4 + wn * 4352;    // 64 rows x 68 words, wave-priv
#pragma unroll
  for (int mf = 0; mf < 4; ++mf)
#pragma unroll
    for (int nf = 0; nf < 4; ++nf)
#pragma unroll
      for (int rg = 0; rg < 4; ++rg)
        scr[(mf * 16 + (lane >> 4) * 4 + rg) * 68 + nf * 16 + (lane & 15)] =
            acc[mf][nf][rg];
  ushort_t* dst = part + (size_t)ksplit * PART_ELEMS;
#pragma unroll
  for (int it = 0; it < 8; ++it) {
    const int row = it * 8 + (lane >> 3);    // m within wave tile
    const int c0 = (lane & 7) * 8;           // n within wave tile
    const float* p = &scr[row * 68 + c0];
    short8 v;
#pragma unroll
    for (int e = 0; e < 8; ++e) v[e] = (short)to_bf16(p[e]);
    const int m = mt * 64 + row;
    const int n = nb * 256 + wn * 64 + c0;
    const int bb = n >> 10, ll = n & 1023;
    __builtin_nontemporal_store(v, (short8*)&dst[(bb * COUT + m) * LPIX + ll]);
  }
}

// -------- add: out = bias[m] + sum of 4 bf16 partials (non-temporal) ------
__global__ void add_kernel(float* __restrict__ out, const ushort_t* __restrict__ part,
                           const float* __restrict__ bias) {
  const int i = (blockIdx.x * 256 + threadIdx.x) * 8;
  const float bv = bias[(i >> 10) & 127];
  f32x4 a0 = (f32x4)bv;
  f32x4 a1 = (f32x4)bv;
#pragma unroll
  for (int j = 0; j < KS; ++j) {
    const short8 pv = __builtin_nontemporal_load(
        (const short8*)&part[(size_t)j * PART_ELEMS + i]);
#pragma unroll
    for (int e = 0; e < 4; ++e) {
      a0[e] += from_bf16((ushort_t)pv[e]);
      a1[e] += from_bf16((ushort_t)pv[e + 4]);
    }
  }
  __builtin_nontemporal_store(a0, (f32x4*)&out[i]);
  __builtin_nontemporal_store(a1, (f32x4*)&out[i + 4]);
}

// ---------------- fallback (only if ws too small): direct evaluation -----
__global__ void naive_kernel(const float* __restrict__ x, const float* __restrict__ wb,
                             const float* __restrict__ wsp, const float* __restrict__ cc,
                             float* __restrict__ out) {
  const int idx = blockIdx.x * 256 + threadIdx.x;
  if (idx >= BATCH * COUT * LPIX) return;
  const int l = idx & 1023, o = (idx >> 10) & 127, b = idx >> 17;
  const int h = l >> 5, w = l & 31;
  float acc = 0.f;
  for (int i = 0; i < CIN; ++i)
    for (int kk = 0; kk < 9; ++kk) {
      const int yy = h + kk / 3 - 1, xx = w + kk % 3 - 1;
      const float v = (yy >= 0 && yy < 32 && xx >= 0 && xx < 32)
                          ? x[((b * CIN + i) * 32 + yy) * 32 + xx] : 0.f;
      float ftr[9];
      basis9(v, ftr);
      const int base = (i * COUT + o) * 9 + kk;
      const float* cp = cc + base * 8;
      float dot = 0.f;
#pragma unroll
      for (int f = 0; f < 8; ++f) dot += cp[f] * ftr[f];
      acc += wsp[base] * dot + wb[base] * ftr[8];
    }
  out[idx] = acc;
}

extern "C" void kernel_launch(void* const* d_in, const int* in_sizes, int n_in,
                              void* d_out, int out_size, void* d_ws, size_t ws_size,
                              hipStream_t stream) {
  const float* x  = (const float*)d_in[0];
  const float* wb = (const float*)d_in[1];
  const float* wsp = (const float*)d_in[2];
  const float* cc = (const float*)d_in[3];
  float* out = (float*)d_out;

  if (ws_size < WS_NEED) {
    naive_kernel<<<(BATCH * COUT * LPIX + 255) / 256, 256, 0, stream>>>(x, wb, wsp, cc, out);
    return;
  }

  char* ws = (char*)d_ws;
  ushort_t* feat = (ushort_t*)ws;
  ushort_t* W    = (ushort_t*)(ws + W_OFF);
  float* bias    = (float*)(ws + BIAS_OFF);
  ushort_t* part = (ushort_t*)(ws + PART_OFF);

  prep_kernel<<<WPREP_BLOCKS + FEAT_BLOCKS, 256, 0, stream>>>(x, feat, wb, wsp, cc, W, bias);
  gemm_kernel<<<64 * 2 * KS, 256, 0, stream>>>(feat, W, part);
  add_kernel<<<PART_ELEMS / 2048, 256, 0, stream>>>(out, part, bias);
}